// Round 3
// baseline (326.158 us; speedup 1.0000x reference)
//
#include <hip/hip_runtime.h>
#include <hip/hip_bf16.h>
#include <stdint.h>

typedef __bf16 bf16_t;
typedef __bf16 bf16x8 __attribute__((ext_vector_type(8)));
typedef float f32x4 __attribute__((ext_vector_type(4)));
typedef unsigned int u32x4 __attribute__((ext_vector_type(4)));

#define NB 4
#define NH 12
#define ND 64
#define NN 2048
#define NC 768
// M = NB*NN = 8192 rows; qkv cols = 3*NC = 2304

// async global->LDS, 16B per lane; lds dest = wave-uniform base + lane*16
__device__ __forceinline__ void async_copy16(const bf16_t* g, bf16_t* l) {
    __builtin_amdgcn_global_load_lds((__attribute__((address_space(1))) void*)(void*)g,
                                     (__attribute__((address_space(3))) void*)l, 16, 0, 0);
}

__device__ __forceinline__ unsigned pack_bf2(float a, float b) {
    union { bf16_t e[2]; unsigned u; } t;
    t.e[0] = (bf16_t)a;
    t.e[1] = (bf16_t)b;
    return t.u;
}

// ---------------- merged cast fp32 -> bf16 (3 segments), 4 elems/thread ----------------
__global__ void cast3_kernel(const float* __restrict__ s0, bf16_t* __restrict__ d0, int n0,
                             const float* __restrict__ s1, bf16_t* __restrict__ d1, int n1,
                             const float* __restrict__ s2, bf16_t* __restrict__ d2, int n2) {
    int i = blockIdx.x * blockDim.x + threadIdx.x;   // float4 units
    const float* s;
    bf16_t* d;
    int j;
    if (i < n0)           { s = s0; d = d0; j = i; }
    else if (i < n0 + n1) { s = s1; d = d1; j = i - n0; }
    else if (i < n0 + n1 + n2) { s = s2; d = d2; j = i - n0 - n1; }
    else return;
    float4 v = ((const float4*)s)[j];
    union { bf16_t e[4]; uint2 u; } t;
    t.e[0] = (bf16_t)v.x; t.e[1] = (bf16_t)v.y; t.e[2] = (bf16_t)v.z; t.e[3] = (bf16_t)v.w;
    ((uint2*)d)[j] = t.u;
}

// key permutation: key s (within 64-tile) -> V storage position
// pos bits {c5,c4,c3,c2,c1,c0} = {s5, s3, s2, s4, s1, s0}  (s0,s1 fixed -> +p stays consecutive)
// Chosen so that storage slot (hh*4+quad)*8 + t holds exactly the key the PV MFMA's
// k-lane layout expects -> V A-frags are contiguous 16B loads both from LDS and global.
__device__ __forceinline__ int vperm(int s) {
    return (s & 32) | (((s >> 2) & 3) << 3) | (((s >> 4) & 1) << 2) | (s & 3);
}

// GEMM LDS tiles: [rows][8 chunks of 16B], XOR swizzle: data chunk c of row r
// lives at chunk position c ^ (r & 7). Measured conflict-free (SQ_LDS_BANK_CONFLICT=0).

// ---------------- QKV GEMM: [8192,2304] = X[8192,768] @ W[2304,768]^T + b ----------------
// R2 measured-best structure: BK=64 single-buffered, A=X, B=W, one launch, grid (64,18).
// Q,K out bf16 [B,H,N,D] (Q pre-scaled by D^-0.5*log2e); V out bf16 [B,H,D,N], keys
// permuted by vperm within each 64-key tile.
__launch_bounds__(256)
__global__ void qkv_gemm_kernel(const bf16_t* __restrict__ X, const bf16_t* __restrict__ W,
                                const float* __restrict__ bias,
                                bf16_t* __restrict__ Q, bf16_t* __restrict__ K, bf16_t* __restrict__ V)
{
    __shared__ __align__(16) bf16_t sA[128 * 64];
    __shared__ __align__(16) bf16_t sB[128 * 64];
    const int tid  = threadIdx.x;
    const int lane = tid & 63;
    const int w    = tid >> 6;
    const int wm   = w & 1, wn = w >> 1;
    const int m0   = blockIdx.x * 128;
    const int n0   = blockIdx.y * 128;
    const int lrow = lane & 15;
    const int quad = lane >> 4;
    const int arow = lane >> 3;
    const int gch  = (lane & 7) ^ arow;   // swizzled source chunk

    f32x4 zero = {0.f, 0.f, 0.f, 0.f};
    f32x4 acc[4][4];
#pragma unroll
    for (int i = 0; i < 4; ++i)
#pragma unroll
        for (int j = 0; j < 4; ++j) acc[i][j] = zero;

    for (int kt = 0; kt < NC; kt += 64) {
        __syncthreads();
        for (int c = w; c < 16; c += 4) {
            async_copy16(X + (size_t)(m0 + c * 8 + arow) * NC + kt + gch * 8, sA + c * 512);
            async_copy16(W + (size_t)(n0 + c * 8 + arow) * NC + kt + gch * 8, sB + c * 512);
        }
        __syncthreads();
#pragma unroll
        for (int hh = 0; hh < 2; ++hh) {
            bf16x8 af[4], bfr[4];
#pragma unroll
            for (int i = 0; i < 4; ++i) {
                int r = wm * 64 + i * 16 + lrow;
                af[i] = *(const bf16x8*)(sA + r * 64 + (((hh * 4 + quad) ^ (r & 7)) * 8));
            }
#pragma unroll
            for (int j = 0; j < 4; ++j) {
                int r = wn * 64 + j * 16 + lrow;
                bfr[j] = *(const bf16x8*)(sB + r * 64 + (((hh * 4 + quad) ^ (r & 7)) * 8));
            }
#pragma unroll
            for (int i = 0; i < 4; ++i)
#pragma unroll
                for (int j = 0; j < 4; ++j)
                    acc[i][j] = __builtin_amdgcn_mfma_f32_16x16x32_bf16(af[i], bfr[j], acc[i][j], 0, 0, 0);
        }
    }

    const int colbase = n0 + wn * 64;       // 64-aligned -> t3,h uniform per wave
    const int t3 = colbase / NC;
    const int h  = (colbase % NC) / ND;
    const float qscale = 0.125f * 1.44269504088896340736f; // D^-0.5 * log2(e)

#pragma unroll
    for (int j = 0; j < 4; ++j) {
        const int d  = j * 16 + lrow;
        const float bv = bias[colbase + d];
#pragma unroll
        for (int i = 0; i < 4; ++i) {
            const int rowg = m0 + wm * 64 + i * 16 + quad * 4;
            const int bb = rowg >> 11;
            const int nn = rowg & 2047;
            if (t3 == 2) {
                union { bf16_t e[4]; uint2 u; } pk;
#pragma unroll
                for (int p = 0; p < 4; ++p) pk.e[p] = (bf16_t)(acc[i][j][p] + bv);
                const int pos = (nn & ~63) | vperm(nn & 63);
                *(uint2*)(V + ((size_t)(bb * NH + h) * ND + d) * NN + pos) = pk.u;
            } else {
                bf16_t* outb = t3 ? K : Q;
#pragma unroll
                for (int p = 0; p < 4; ++p) {
                    float val = acc[i][j][p] + bv;
                    if (t3 == 0) val *= qscale;
                    outb[((size_t)(bb * NH + h) * NN + nn + p) * ND + d] = (bf16_t)val;
                }
            }
        }
    }
}

// ---------------- flash attention v4: register-direct + 1-step SW pipeline ----------------
// R3 post-mortem chain: R0 (LDS dbuf, 4 waves) = 71.6us, pipes phase-locked by per-step
// barrier (MFMA 33 / VALU 43, overlap ~43%). R2 (register-direct, no prefetch) = 183us:
// loads consumed same-step -> full L2 latency serialized per step. Fix: keep the
// barrier-free register-direct structure but issue next tile's K/V frag loads a FULL step
// before use (two named register stages, manual 2x unroll, rule #20). Load-to-use distance
// ~1300 wave-cycles >> L2 latency; zero barriers so waves drift and complementary phases
// overlap across the 8 waves/CU. exp2 fused into S loop (kills s[2][4] live range);
// VGPR ~240 -> __launch_bounds__(256,2). setprio(1) wraps the pure-MFMA l+PV cluster (T5,
// drifting-wave regime). Tail prefetch reads <=64 elems past the head; lands in the next
// workspace buffer (kb->vb->ab all allocated), values unused.
// Wave w owns q rows [w*32, w*32+32). S^T = K.Q^T: lane holds q = lane&15,
// key = blk*16+quad*4+p. exp2 packed straight into PV B-frags; l via ones-row MFMA.
#define ATTN_STEP(CK, CV, NK, NV)                                                                   \
    {                                                                                               \
        _Pragma("unroll")                                                                           \
        for (int blk = 0; blk < 4; ++blk)                                                           \
            _Pragma("unroll")                                                                       \
            for (int hh = 0; hh < 2; ++hh)                                                          \
                NK[blk][hh] = *(const bf16x8*)(kpl + blk * 16 * ND + hh * 32);                       \
        _Pragma("unroll")                                                                           \
        for (int db = 0; db < 4; ++db)                                                              \
            _Pragma("unroll")                                                                       \
            for (int hh = 0; hh < 2; ++hh)                                                          \
                NV[db][hh] = *(const bf16x8*)(vpl + db * 16 * NN + hh * 32);                         \
        kpl += (size_t)64 * ND;                                                                     \
        vpl += 64;                                                                                  \
        bf16x8 pe[2][2];                                                                            \
        _Pragma("unroll")                                                                           \
        for (int qi = 0; qi < 2; ++qi) {                                                            \
            u32x4 pu0 = {0, 0, 0, 0}, pu1 = {0, 0, 0, 0};                                           \
            _Pragma("unroll")                                                                       \
            for (int blk = 0; blk < 4; ++blk) {                                                     \
                f32x4 z = zero;                                                                     \
                z = __builtin_amdgcn_mfma_f32_16x16x32_bf16(CK[blk][0], qb[qi][0], z, 0, 0, 0);     \
                z = __builtin_amdgcn_mfma_f32_16x16x32_bf16(CK[blk][1], qb[qi][1], z, 0, 0, 0);     \
                unsigned lo = pack_bf2(__builtin_amdgcn_exp2f(z[0]), __builtin_amdgcn_exp2f(z[1])); \
                unsigned hi = pack_bf2(__builtin_amdgcn_exp2f(z[2]), __builtin_amdgcn_exp2f(z[3])); \
                if (blk == 0)      { pu0[0] = lo; pu0[1] = hi; }                                    \
                else if (blk == 1) { pu0[2] = lo; pu0[3] = hi; }                                    \
                else if (blk == 2) { pu1[0] = lo; pu1[1] = hi; }                                    \
                else               { pu1[2] = lo; pu1[3] = hi; }                                    \
            }                                                                                       \
            pe[qi][0] = __builtin_bit_cast(bf16x8, pu0);                                            \
            pe[qi][1] = __builtin_bit_cast(bf16x8, pu1);                                            \
        }                                                                                           \
        __builtin_amdgcn_s_setprio(1);                                                              \
        _Pragma("unroll")                                                                           \
        for (int qi = 0; qi < 2; ++qi) {                                                            \
            lacc[qi] = __builtin_amdgcn_mfma_f32_16x16x32_bf16(ones, pe[qi][0], lacc[qi], 0, 0, 0); \
            lacc[qi] = __builtin_amdgcn_mfma_f32_16x16x32_bf16(ones, pe[qi][1], lacc[qi], 0, 0, 0); \
        }                                                                                           \
        _Pragma("unroll")                                                                           \
        for (int db = 0; db < 4; ++db)                                                              \
            _Pragma("unroll")                                                                       \
            for (int qi = 0; qi < 2; ++qi) {                                                        \
                o[qi][db] = __builtin_amdgcn_mfma_f32_16x16x32_bf16(CV[db][0], pe[qi][0], o[qi][db], 0, 0, 0); \
                o[qi][db] = __builtin_amdgcn_mfma_f32_16x16x32_bf16(CV[db][1], pe[qi][1], o[qi][db], 0, 0, 0); \
            }                                                                                       \
        __builtin_amdgcn_s_setprio(0);                                                              \
    }

__launch_bounds__(256, 2)
__global__ void attn_kernel(const bf16_t* __restrict__ Q, const bf16_t* __restrict__ K,
                            const bf16_t* __restrict__ Vt, bf16_t* __restrict__ O)
{
    const int tid  = threadIdx.x;
    const int lane = tid & 63;
    const int w    = tid >> 6;          // 0..3
    const int qt   = blockIdx.x;
    const int h    = blockIdx.y;
    const int b    = blockIdx.z;
    const int lrow = lane & 15;
    const int quad = lane >> 4;
    const size_t head_off = (size_t)(b * NH + h) * NN * ND;
    const bf16_t* qh = Q  + head_off;
    const bf16_t* kh = K  + head_off;
    const bf16_t* vh = Vt + head_off;   // [d][pos], vperm'd within each 64-key tile

    // Q frags direct from global: B-operand rows n = q = w*32+qi*16+lrow, k = hh*32+quad*8..
    bf16x8 qb[2][2];
#pragma unroll
    for (int qi = 0; qi < 2; ++qi)
#pragma unroll
        for (int hh = 0; hh < 2; ++hh)
            qb[qi][hh] = *(const bf16x8*)(qh + (size_t)(qt * 128 + w * 32 + qi * 16 + lrow) * ND
                                             + hh * 32 + quad * 8);

    // ones A-frag for the l row-sum MFMA
    bf16x8 ones;
#pragma unroll
    for (int p = 0; p < 8; ++p) ones[p] = (bf16_t)1.0f;

    f32x4 zero = {0.f, 0.f, 0.f, 0.f};
    f32x4 o[2][4];
#pragma unroll
    for (int qi = 0; qi < 2; ++qi)
#pragma unroll
        for (int db = 0; db < 4; ++db) o[qi][db] = zero;
    f32x4 lacc[2] = {zero, zero};

    // per-lane streaming bases: K frag (blk,hh) at kpl + blk*16*ND + hh*32, step stride 64*ND
    //                           V frag (db,hh)  at vpl + db*16*NN + hh*32, step stride 64
    const bf16_t* kpl = kh + (size_t)lrow * ND + quad * 8;
    const bf16_t* vpl = vh + (size_t)lrow * NN + quad * 8;

    // prologue: tile 0 into stage A
    bf16x8 kA[4][2], vA[4][2], kB[4][2], vB[4][2];
#pragma unroll
    for (int blk = 0; blk < 4; ++blk)
#pragma unroll
        for (int hh = 0; hh < 2; ++hh) {
            kA[blk][hh] = *(const bf16x8*)(kpl + blk * 16 * ND + hh * 32);
            vA[blk][hh] = *(const bf16x8*)(vpl + blk * 16 * NN + hh * 32);
        }
    kpl += (size_t)64 * ND;
    vpl += 64;

    for (int it = 0; it < NN / 128; ++it) {   // 16 double-steps = 32 kv tiles
        ATTN_STEP(kA, vA, kB, vB);
        ATTN_STEP(kB, vB, kA, vA);
    }

    // write attn out bf16 [B,N,C], col = h*64 + d; 4 consecutive d per store
#pragma unroll
    for (int qi = 0; qi < 2; ++qi) {
        const float rl = 1.0f / lacc[qi][0];
        const int n = qt * 128 + w * 32 + qi * 16 + lrow;
        const size_t rowoff = ((size_t)(b * NN + n)) * NC + h * ND;
#pragma unroll
        for (int db = 0; db < 4; ++db) {
            union { bf16_t e[4]; uint2 u; } pk;
#pragma unroll
            for (int p = 0; p < 4; ++p) pk.e[p] = (bf16_t)(o[qi][db][p] * rl);
            *(uint2*)(O + rowoff + db * 16 + quad * 4) = pk.u;
        }
    }
}

// ---------------- proj GEMM: out[8192,768] = A[8192,768] @ W[768,768]^T + b (fp32) ----------------
// R2 measured-best structure: 128x128 tiles, BK=64 single-buffered, non-swapped operands,
// scalar fp32 stores (coalesced across lrow lanes). Grid (64,6).
__launch_bounds__(256)
__global__ void proj_gemm_kernel(const bf16_t* __restrict__ A, const bf16_t* __restrict__ W,
                                 const float* __restrict__ bias, float* __restrict__ out)
{
    __shared__ __align__(16) bf16_t sA[128 * 64];
    __shared__ __align__(16) bf16_t sB[128 * 64];
    const int tid  = threadIdx.x;
    const int lane = tid & 63;
    const int w    = tid >> 6;
    const int wm   = w & 1, wn = w >> 1;
    const int m0   = blockIdx.x * 128;
    const int n0   = blockIdx.y * 128;
    const int lrow = lane & 15;
    const int quad = lane >> 4;
    const int arow = lane >> 3;
    const int gch  = (lane & 7) ^ arow;

    f32x4 zero = {0.f, 0.f, 0.f, 0.f};
    f32x4 acc[4][4];
#pragma unroll
    for (int i = 0; i < 4; ++i)
#pragma unroll
        for (int j = 0; j < 4; ++j) acc[i][j] = zero;

    for (int kt = 0; kt < NC; kt += 64) {
        __syncthreads();
        for (int c = w; c < 16; c += 4) {
            async_copy16(A + (size_t)(m0 + c * 8 + arow) * NC + kt + gch * 8, sA + c * 512);
            async_copy16(W + (size_t)(n0 + c * 8 + arow) * NC + kt + gch * 8, sB + c * 512);
        }
        __syncthreads();
#pragma unroll
        for (int hh = 0; hh < 2; ++hh) {
            bf16x8 af[4], bfr[4];
#pragma unroll
            for (int i = 0; i < 4; ++i) {
                int r = wm * 64 + i * 16 + lrow;
                af[i] = *(const bf16x8*)(sA + r * 64 + (((hh * 4 + quad) ^ (r & 7)) * 8));
            }
#pragma unroll
            for (int j = 0; j < 4; ++j) {
                int r = wn * 64 + j * 16 + lrow;
                bfr[j] = *(const bf16x8*)(sB + r * 64 + (((hh * 4 + quad) ^ (r & 7)) * 8));
            }
#pragma unroll
            for (int i = 0; i < 4; ++i)
#pragma unroll
                for (int j = 0; j < 4; ++j)
                    acc[i][j] = __builtin_amdgcn_mfma_f32_16x16x32_bf16(af[i], bfr[j], acc[i][j], 0, 0, 0);
        }
    }

#pragma unroll
    for (int j = 0; j < 4; ++j) {
        const int colg = n0 + wn * 64 + j * 16 + lrow;
        const float bv = bias[colg];
#pragma unroll
        for (int i = 0; i < 4; ++i) {
            const int rowg = m0 + wm * 64 + i * 16 + quad * 4;
#pragma unroll
            for (int p = 0; p < 4; ++p)
                out[(size_t)(rowg + p) * NC + colg] = acc[i][j][p] + bv;
        }
    }
}

extern "C" void kernel_launch(void* const* d_in, const int* in_sizes, int n_in,
                              void* d_out, int out_size, void* d_ws, size_t ws_size,
                              hipStream_t stream) {
    const float* x      = (const float*)d_in[0];
    const float* qkv_w  = (const float*)d_in[1];
    const float* qkv_b  = (const float*)d_in[2];
    const float* proj_w = (const float*)d_in[3];
    const float* proj_b = (const float*)d_in[4];
    float* out = (float*)d_out;

    char* ws = (char*)d_ws;
    bf16_t* xb    = (bf16_t*)ws; ws += (size_t)8192 * 768 * 2;
    bf16_t* wqkv  = (bf16_t*)ws; ws += (size_t)2304 * 768 * 2;
    bf16_t* wproj = (bf16_t*)ws; ws += (size_t)768 * 768 * 2;
    bf16_t* qb    = (bf16_t*)ws; ws += (size_t)NB * NH * NN * ND * 2;  // [B,H,N,D]
    bf16_t* kb    = (bf16_t*)ws; ws += (size_t)NB * NH * NN * ND * 2;  // [B,H,N,D]
    bf16_t* vb    = (bf16_t*)ws; ws += (size_t)NB * NH * NN * ND * 2;  // [B,H,D,N] permuted
    bf16_t* ab    = (bf16_t*)ws; ws += (size_t)8192 * 768 * 2;         // attn out [B,N,C]

    const int c0 = 8192 * 768 / 4, c1 = 2304 * 768 / 4, c2 = 768 * 768 / 4;
    cast3_kernel<<<(c0 + c1 + c2 + 255) / 256, 256, 0, stream>>>(x, xb, c0, qkv_w, wqkv, c1, proj_w, wproj, c2);

    qkv_gemm_kernel<<<dim3(8192 / 128, 2304 / 128), 256, 0, stream>>>(xb, wqkv, qkv_b, qb, kb, vb);
    attn_kernel<<<dim3(NN / 128, NH, NB), 256, 0, stream>>>(qb, kb, vb, ab);
    proj_gemm_kernel<<<dim3(8192 / 128, 768 / 128), 256, 0, stream>>>(ab, wproj, proj_b, out);
}

// Round 4
// 211.951 us; speedup vs baseline: 1.5388x; 1.5388x over previous
//
#include <hip/hip_runtime.h>
#include <hip/hip_bf16.h>
#include <stdint.h>

typedef __bf16 bf16_t;
typedef __bf16 bf16x8 __attribute__((ext_vector_type(8)));
typedef float f32x4 __attribute__((ext_vector_type(4)));
typedef unsigned int u32x4 __attribute__((ext_vector_type(4)));

#define NB 4
#define NH 12
#define ND 64
#define NN 2048
#define NC 768
// M = NB*NN = 8192 rows; qkv cols = 3*NC = 2304

// async global->LDS, 16B per lane; lds dest = wave-uniform base + lane*16
__device__ __forceinline__ void async_copy16(const bf16_t* g, bf16_t* l) {
    __builtin_amdgcn_global_load_lds((__attribute__((address_space(1))) void*)(void*)g,
                                     (__attribute__((address_space(3))) void*)l, 16, 0, 0);
}

__device__ __forceinline__ unsigned pack_bf2(float a, float b) {
    union { bf16_t e[2]; unsigned u; } t;
    t.e[0] = (bf16_t)a;
    t.e[1] = (bf16_t)b;
    return t.u;
}

// ---------------- merged cast fp32 -> bf16 (3 segments), 4 elems/thread ----------------
__global__ void cast3_kernel(const float* __restrict__ s0, bf16_t* __restrict__ d0, int n0,
                             const float* __restrict__ s1, bf16_t* __restrict__ d1, int n1,
                             const float* __restrict__ s2, bf16_t* __restrict__ d2, int n2) {
    int i = blockIdx.x * blockDim.x + threadIdx.x;   // float4 units
    const float* s;
    bf16_t* d;
    int j;
    if (i < n0)           { s = s0; d = d0; j = i; }
    else if (i < n0 + n1) { s = s1; d = d1; j = i - n0; }
    else if (i < n0 + n1 + n2) { s = s2; d = d2; j = i - n0 - n1; }
    else return;
    float4 v = ((const float4*)s)[j];
    union { bf16_t e[4]; uint2 u; } t;
    t.e[0] = (bf16_t)v.x; t.e[1] = (bf16_t)v.y; t.e[2] = (bf16_t)v.z; t.e[3] = (bf16_t)v.w;
    ((uint2*)d)[j] = t.u;
}

// key permutation: key s (within 64-tile) -> V storage position
// pos bits {c5,c4,c3,c2,c1,c0} = {s5, s3, s2, s4, s1, s0}  (s0,s1 fixed -> +p stays consecutive)
__device__ __forceinline__ int vperm(int s) {
    return (s & 32) | (((s >> 2) & 3) << 3) | (((s >> 4) & 1) << 2) | (s & 3);
}

// GEMM/attn LDS tiles: [rows][8 chunks of 16B], XOR swizzle: data chunk c of row r
// lives at chunk position c ^ (r & 7). Measured conflict-free (SQ_LDS_BANK_CONFLICT=0).

// ---------------- QKV GEMM: [8192,2304] = X[8192,768] @ W[2304,768]^T + b ----------------
// R2 measured-best structure: BK=64 single-buffered, A=X, B=W, one launch, grid (64,18).
// Q,K out bf16 [B,H,N,D] (Q pre-scaled by D^-0.5*log2e); V out bf16 [B,H,D,N], keys
// permuted by vperm within each 64-key tile.
__launch_bounds__(256)
__global__ void qkv_gemm_kernel(const bf16_t* __restrict__ X, const bf16_t* __restrict__ W,
                                const float* __restrict__ bias,
                                bf16_t* __restrict__ Q, bf16_t* __restrict__ K, bf16_t* __restrict__ V)
{
    __shared__ __align__(16) bf16_t sA[128 * 64];
    __shared__ __align__(16) bf16_t sB[128 * 64];
    const int tid  = threadIdx.x;
    const int lane = tid & 63;
    const int w    = tid >> 6;
    const int wm   = w & 1, wn = w >> 1;
    const int m0   = blockIdx.x * 128;
    const int n0   = blockIdx.y * 128;
    const int lrow = lane & 15;
    const int quad = lane >> 4;
    const int arow = lane >> 3;
    const int gch  = (lane & 7) ^ arow;   // swizzled source chunk

    f32x4 zero = {0.f, 0.f, 0.f, 0.f};
    f32x4 acc[4][4];
#pragma unroll
    for (int i = 0; i < 4; ++i)
#pragma unroll
        for (int j = 0; j < 4; ++j) acc[i][j] = zero;

    for (int kt = 0; kt < NC; kt += 64) {
        __syncthreads();
        for (int c = w; c < 16; c += 4) {
            async_copy16(X + (size_t)(m0 + c * 8 + arow) * NC + kt + gch * 8, sA + c * 512);
            async_copy16(W + (size_t)(n0 + c * 8 + arow) * NC + kt + gch * 8, sB + c * 512);
        }
        __syncthreads();
#pragma unroll
        for (int hh = 0; hh < 2; ++hh) {
            bf16x8 af[4], bfr[4];
#pragma unroll
            for (int i = 0; i < 4; ++i) {
                int r = wm * 64 + i * 16 + lrow;
                af[i] = *(const bf16x8*)(sA + r * 64 + (((hh * 4 + quad) ^ (r & 7)) * 8));
            }
#pragma unroll
            for (int j = 0; j < 4; ++j) {
                int r = wn * 64 + j * 16 + lrow;
                bfr[j] = *(const bf16x8*)(sB + r * 64 + (((hh * 4 + quad) ^ (r & 7)) * 8));
            }
#pragma unroll
            for (int i = 0; i < 4; ++i)
#pragma unroll
                for (int j = 0; j < 4; ++j)
                    acc[i][j] = __builtin_amdgcn_mfma_f32_16x16x32_bf16(af[i], bfr[j], acc[i][j], 0, 0, 0);
        }
    }

    const int colbase = n0 + wn * 64;       // 64-aligned -> t3,h uniform per wave
    const int t3 = colbase / NC;
    const int h  = (colbase % NC) / ND;
    const float qscale = 0.125f * 1.44269504088896340736f; // D^-0.5 * log2(e)

#pragma unroll
    for (int j = 0; j < 4; ++j) {
        const int d  = j * 16 + lrow;
        const float bv = bias[colbase + d];
#pragma unroll
        for (int i = 0; i < 4; ++i) {
            const int rowg = m0 + wm * 64 + i * 16 + quad * 4;
            const int bb = rowg >> 11;
            const int nn = rowg & 2047;
            if (t3 == 2) {
                union { bf16_t e[4]; uint2 u; } pk;
#pragma unroll
                for (int p = 0; p < 4; ++p) pk.e[p] = (bf16_t)(acc[i][j][p] + bv);
                const int pos = (nn & ~63) | vperm(nn & 63);
                *(uint2*)(V + ((size_t)(bb * NH + h) * ND + d) * NN + pos) = pk.u;
            } else {
                bf16_t* outb = t3 ? K : Q;
#pragma unroll
                for (int p = 0; p < 4; ++p) {
                    float val = acc[i][j][p] + bv;
                    if (t3 == 0) val *= qscale;
                    outb[((size_t)(bb * NH + h) * NN + nn + p) * ND + d] = (bf16_t)val;
                }
            }
        }
    }
}

// ---------------- flash attention v5: R0 structure + tri-buffer + counted vmcnt (T4) ----------------
// R4 post-mortem chain: R0 (LDS dbuf, __syncthreads) = 71.6us best; counters MFMA 33 +
// VALU 43 = 76% issue-sum, ~24% = the s_waitcnt vmcnt(0) drain the compiler emits before
// every s_barrier (m97-ceiling mechanism). R2/R3 (register-direct) = 183/189us: compiler
// re-sinks "prefetched" loads to their consumers (defeats SW pipelines) AND 4x L2/L3
// traffic (every wave reads the full tile from cache instead of LDS). Fix here: keep R0's
// compute body + cooperative global_load_lds staging EXACTLY, but tri-buffer (3x16KB,
// still 3 blocks/CU) with 2-step prefetch distance, raw s_barrier, and counted
// s_waitcnt vmcnt(4) (T4: never drain to 0 in the loop). Invariant: wave reaches barrier
// k only after ITS stage(t+1) loads retired => after barrier, buf[t+1] fully visible;
// stage(t+2) overwrites a buffer last read at step t-1, which all waves finished before
// the previous barrier. Uniform control flow; "memory"-clobber asm + sched_barrier(0)
// fences (rule #18). setprio(1) wraps MFMA clusters (T5, drifting-block regime).
// Wave w owns q rows [w*32, w*32+32). S^T = K.Q^T: lane holds q = lane&15, key =
// blk*16+quad*4+p. exp2 packed straight into PV B-frags (V vperm'd); l via ones-MFMA.
#define WAIT_BAR(N)                                              \
    asm volatile("s_waitcnt vmcnt(" #N ")" ::: "memory");        \
    __builtin_amdgcn_sched_barrier(0);                           \
    __builtin_amdgcn_s_barrier();                                \
    __builtin_amdgcn_sched_barrier(0);

#define STAGE(BUF)                                               \
    {                                                            \
        bf16_t* dK = sK[BUF] + w * 1024;                         \
        bf16_t* dV = sV[BUF] + w * 1024;                         \
        async_copy16(kp,          dK);                           \
        async_copy16(kp + 8 * ND, dK + 512);                     \
        async_copy16(vp,          dV);                           \
        async_copy16(vp + 8 * NN, dV + 512);                     \
        kp += (size_t)64 * ND; vp += 64;                         \
    }

#define ATTN_COMPUTE(CUR)                                                                            \
    {                                                                                                \
        const bf16_t* sKh = sK[CUR];                                                                 \
        const bf16_t* sVh = sV[CUR];                                                                 \
        f32x4 s[2][4];                                                                               \
        __builtin_amdgcn_s_setprio(1);                                                               \
        _Pragma("unroll")                                                                            \
        for (int blk = 0; blk < 4; ++blk) {                                                          \
            bf16x8 a0 = *(const bf16x8*)(sKh + off[blk][0]);                                         \
            bf16x8 a1 = *(const bf16x8*)(sKh + off[blk][1]);                                         \
            _Pragma("unroll")                                                                        \
            for (int qi = 0; qi < 2; ++qi) {                                                         \
                f32x4 z = zero;                                                                      \
                z = __builtin_amdgcn_mfma_f32_16x16x32_bf16(a0, qb[qi][0], z, 0, 0, 0);              \
                z = __builtin_amdgcn_mfma_f32_16x16x32_bf16(a1, qb[qi][1], z, 0, 0, 0);              \
                s[qi][blk] = z;                                                                      \
            }                                                                                        \
        }                                                                                            \
        __builtin_amdgcn_s_setprio(0);                                                               \
        bf16x8 pe[2][2];                                                                             \
        _Pragma("unroll")                                                                            \
        for (int qi = 0; qi < 2; ++qi) {                                                             \
            u32x4 pu0 = {0, 0, 0, 0}, pu1 = {0, 0, 0, 0};                                            \
            _Pragma("unroll")                                                                        \
            for (int blk = 0; blk < 4; ++blk) {                                                      \
                float e0 = __builtin_amdgcn_exp2f(s[qi][blk][0]);                                    \
                float e1 = __builtin_amdgcn_exp2f(s[qi][blk][1]);                                    \
                float e2 = __builtin_amdgcn_exp2f(s[qi][blk][2]);                                    \
                float e3 = __builtin_amdgcn_exp2f(s[qi][blk][3]);                                    \
                unsigned lo = pack_bf2(e0, e1), hi = pack_bf2(e2, e3);                               \
                if (blk == 0)      { pu0[0] = lo; pu0[1] = hi; }                                     \
                else if (blk == 1) { pu0[2] = lo; pu0[3] = hi; }                                     \
                else if (blk == 2) { pu1[0] = lo; pu1[1] = hi; }                                     \
                else               { pu1[2] = lo; pu1[3] = hi; }                                     \
            }                                                                                        \
            pe[qi][0] = __builtin_bit_cast(bf16x8, pu0);                                             \
            pe[qi][1] = __builtin_bit_cast(bf16x8, pu1);                                             \
        }                                                                                            \
        __builtin_amdgcn_s_setprio(1);                                                               \
        _Pragma("unroll")                                                                            \
        for (int qi = 0; qi < 2; ++qi) {                                                             \
            lacc[qi] = __builtin_amdgcn_mfma_f32_16x16x32_bf16(ones, pe[qi][0], lacc[qi], 0, 0, 0);  \
            lacc[qi] = __builtin_amdgcn_mfma_f32_16x16x32_bf16(ones, pe[qi][1], lacc[qi], 0, 0, 0);  \
        }                                                                                            \
        _Pragma("unroll")                                                                            \
        for (int db = 0; db < 4; ++db) {                                                             \
            bf16x8 v0 = *(const bf16x8*)(sVh + off[db][0]);                                          \
            bf16x8 v1 = *(const bf16x8*)(sVh + off[db][1]);                                          \
            _Pragma("unroll")                                                                        \
            for (int qi = 0; qi < 2; ++qi) {                                                         \
                o[qi][db] = __builtin_amdgcn_mfma_f32_16x16x32_bf16(v0, pe[qi][0], o[qi][db], 0, 0, 0); \
                o[qi][db] = __builtin_amdgcn_mfma_f32_16x16x32_bf16(v1, pe[qi][1], o[qi][db], 0, 0, 0); \
            }                                                                                        \
        }                                                                                            \
        __builtin_amdgcn_s_setprio(0);                                                               \
    }

__launch_bounds__(256, 3)
__global__ void attn_kernel(const bf16_t* __restrict__ Q, const bf16_t* __restrict__ K,
                            const bf16_t* __restrict__ Vt, bf16_t* __restrict__ O)
{
    __shared__ __align__(16) bf16_t sK[3][64 * 64];
    __shared__ __align__(16) bf16_t sV[3][64 * 64];   // [d][pos]
    bf16_t* sQ = sK[0];   // Q tile (16 KB) overlays sK[0..1] during init
    const int tid  = threadIdx.x;
    const int lane = tid & 63;
    const int w    = tid >> 6;          // 0..3
    const int qt   = blockIdx.x;
    const int h    = blockIdx.y;
    const int b    = blockIdx.z;
    const int lrow = lane & 15;
    const int quad = lane >> 4;
    const int arow = lane >> 3;
    const int gch  = (lane & 7) ^ arow;
    const size_t head_off = (size_t)(b * NH + h) * NN * ND;
    const bf16_t* qh = Q  + head_off;
    const bf16_t* kh = K  + head_off;
    const bf16_t* vh = Vt + head_off;   // [d][n]

    // stage Q tile [128 x 64]: wave w stages chunks 4w..4w+3
#pragma unroll
    for (int c = 0; c < 4; ++c)
        async_copy16(qh + (size_t)(qt * 128 + (w * 4 + c) * 8 + arow) * ND + gch * 8,
                     sQ + (w * 4 + c) * 512);
    __syncthreads();

    bf16x8 qb[2][2];
#pragma unroll
    for (int qi = 0; qi < 2; ++qi)
#pragma unroll
        for (int hh = 0; hh < 2; ++hh) {
            int r = w * 32 + qi * 16 + lrow;
            qb[qi][hh] = *(const bf16x8*)(sQ + r * 64 + (((hh * 4 + quad) ^ (r & 7)) * 8));
        }
    __syncthreads();   // all waves done reading Q before K staging overwrites it

    // ones A-frag for the l row-sum MFMA
    bf16x8 ones;
#pragma unroll
    for (int p = 0; p < 8; ++p) ones[p] = (bf16_t)1.0f;

    // frag offsets (elements), rows blk*16+lrow, two 32-k halves
    int off[4][2];
#pragma unroll
    for (int blk = 0; blk < 4; ++blk) {
        int r = blk * 16 + lrow;
        off[blk][0] = r * 64 + ((quad ^ (r & 7)) * 8);
        off[blk][1] = r * 64 + (((4 + quad) ^ (r & 7)) * 8);
    }

    f32x4 zero = {0.f, 0.f, 0.f, 0.f};
    f32x4 o[2][4];
#pragma unroll
    for (int qi = 0; qi < 2; ++qi)
#pragma unroll
        for (int db = 0; db < 4; ++db) o[qi][db] = zero;
    f32x4 lacc[2] = {zero, zero};

    // staging: wave w covers rows [w*16, w*16+16) of each 64-row step tile
    const bf16_t* kp = kh + (size_t)(w * 16 + arow) * ND + gch * 8;
    const bf16_t* vp = vh + (size_t)(w * 16 + arow) * NN + gch * 8;

    // prologue: stage tiles 0,1 into bufs 0,1; wait only for tile 0 (tile 1 stays in flight)
    STAGE(0);
    STAGE(1);
    WAIT_BAR(4);

    int cur = 0;
    for (int it = 0; it < NN / 64 - 2; ++it) {
        int nxt = cur + 2; if (nxt >= 3) nxt -= 3;
        STAGE(nxt);                 // tile it+2; outstanding: 8 (tiles it+1, it+2)
        ATTN_COMPUTE(cur);          // tile it
        WAIT_BAR(4);                // my tile-(it+1) loads retired; it+2 stays in flight
        cur = (cur + 1 == 3) ? 0 : cur + 1;
    }
    // tile NN/64-2: nothing left to stage; ensure final tile landed before last step
    ATTN_COMPUTE(cur);
    WAIT_BAR(0);
    cur = (cur + 1 == 3) ? 0 : cur + 1;
    ATTN_COMPUTE(cur);

    // write attn out bf16 [B,N,C], col = h*64 + d; 4 consecutive d per store
#pragma unroll
    for (int qi = 0; qi < 2; ++qi) {
        const float rl = 1.0f / lacc[qi][0];
        const int n = qt * 128 + w * 32 + qi * 16 + lrow;
        const size_t rowoff = ((size_t)(b * NN + n)) * NC + h * ND;
#pragma unroll
        for (int db = 0; db < 4; ++db) {
            union { bf16_t e[4]; uint2 u; } pk;
#pragma unroll
            for (int p = 0; p < 4; ++p) pk.e[p] = (bf16_t)(o[qi][db][p] * rl);
            *(uint2*)(O + rowoff + db * 16 + quad * 4) = pk.u;
        }
    }
}

// ---------------- proj GEMM: out[8192,768] = A[8192,768] @ W[768,768]^T + b (fp32) ----------------
// R2 measured-best structure: 128x128 tiles, BK=64 single-buffered, non-swapped operands,
// scalar fp32 stores (coalesced across lrow lanes). Grid (64,6).
__launch_bounds__(256)
__global__ void proj_gemm_kernel(const bf16_t* __restrict__ A, const bf16_t* __restrict__ W,
                                 const float* __restrict__ bias, float* __restrict__ out)
{
    __shared__ __align__(16) bf16_t sA[128 * 64];
    __shared__ __align__(16) bf16_t sB[128 * 64];
    const int tid  = threadIdx.x;
    const int lane = tid & 63;
    const int w    = tid >> 6;
    const int wm   = w & 1, wn = w >> 1;
    const int m0   = blockIdx.x * 128;
    const int n0   = blockIdx.y * 128;
    const int lrow = lane & 15;
    const int quad = lane >> 4;
    const int arow = lane >> 3;
    const int gch  = (lane & 7) ^ arow;

    f32x4 zero = {0.f, 0.f, 0.f, 0.f};
    f32x4 acc[4][4];
#pragma unroll
    for (int i = 0; i < 4; ++i)
#pragma unroll
        for (int j = 0; j < 4; ++j) acc[i][j] = zero;

    for (int kt = 0; kt < NC; kt += 64) {
        __syncthreads();
        for (int c = w; c < 16; c += 4) {
            async_copy16(A + (size_t)(m0 + c * 8 + arow) * NC + kt + gch * 8, sA + c * 512);
            async_copy16(W + (size_t)(n0 + c * 8 + arow) * NC + kt + gch * 8, sB + c * 512);
        }
        __syncthreads();
#pragma unroll
        for (int hh = 0; hh < 2; ++hh) {
            bf16x8 af[4], bfr[4];
#pragma unroll
            for (int i = 0; i < 4; ++i) {
                int r = wm * 64 + i * 16 + lrow;
                af[i] = *(const bf16x8*)(sA + r * 64 + (((hh * 4 + quad) ^ (r & 7)) * 8));
            }
#pragma unroll
            for (int j = 0; j < 4; ++j) {
                int r = wn * 64 + j * 16 + lrow;
                bfr[j] = *(const bf16x8*)(sB + r * 64 + (((hh * 4 + quad) ^ (r & 7)) * 8));
            }
#pragma unroll
            for (int i = 0; i < 4; ++i)
#pragma unroll
                for (int j = 0; j < 4; ++j)
                    acc[i][j] = __builtin_amdgcn_mfma_f32_16x16x32_bf16(af[i], bfr[j], acc[i][j], 0, 0, 0);
        }
    }

#pragma unroll
    for (int j = 0; j < 4; ++j) {
        const int colg = n0 + wn * 64 + j * 16 + lrow;
        const float bv = bias[colg];
#pragma unroll
        for (int i = 0; i < 4; ++i) {
            const int rowg = m0 + wm * 64 + i * 16 + quad * 4;
#pragma unroll
            for (int p = 0; p < 4; ++p)
                out[(size_t)(rowg + p) * NC + colg] = acc[i][j][p] + bv;
        }
    }
}

extern "C" void kernel_launch(void* const* d_in, const int* in_sizes, int n_in,
                              void* d_out, int out_size, void* d_ws, size_t ws_size,
                              hipStream_t stream) {
    const float* x      = (const float*)d_in[0];
    const float* qkv_w  = (const float*)d_in[1];
    const float* qkv_b  = (const float*)d_in[2];
    const float* proj_w = (const float*)d_in[3];
    const float* proj_b = (const float*)d_in[4];
    float* out = (float*)d_out;

    char* ws = (char*)d_ws;
    bf16_t* xb    = (bf16_t*)ws; ws += (size_t)8192 * 768 * 2;
    bf16_t* wqkv  = (bf16_t*)ws; ws += (size_t)2304 * 768 * 2;
    bf16_t* wproj = (bf16_t*)ws; ws += (size_t)768 * 768 * 2;
    bf16_t* qb    = (bf16_t*)ws; ws += (size_t)NB * NH * NN * ND * 2;  // [B,H,N,D]
    bf16_t* kb    = (bf16_t*)ws; ws += (size_t)NB * NH * NN * ND * 2;  // [B,H,N,D]
    bf16_t* vb    = (bf16_t*)ws; ws += (size_t)NB * NH * NN * ND * 2;  // [B,H,D,N] permuted
    bf16_t* ab    = (bf16_t*)ws; ws += (size_t)8192 * 768 * 2;         // attn out [B,N,C]

    const int c0 = 8192 * 768 / 4, c1 = 2304 * 768 / 4, c2 = 768 * 768 / 4;
    cast3_kernel<<<(c0 + c1 + c2 + 255) / 256, 256, 0, stream>>>(x, xb, c0, qkv_w, wqkv, c1, proj_w, wproj, c2);

    qkv_gemm_kernel<<<dim3(8192 / 128, 2304 / 128), 256, 0, stream>>>(xb, wqkv, qkv_b, qb, kb, vb);
    attn_kernel<<<dim3(NN / 128, NH, NB), 256, 0, stream>>>(qb, kb, vb, ab);
    proj_gemm_kernel<<<dim3(8192 / 128, 768 / 128), 256, 0, stream>>>(ab, wproj, proj_b, out);
}